// Round 5
// baseline (5133.788 us; speedup 1.0000x reference)
//
#include <hip/hip_runtime.h>
#include <hip/hip_bf16.h>

typedef __bf16 bf16x8 __attribute__((ext_vector_type(8)));
typedef float  f32x4  __attribute__((ext_vector_type(4)));

constexpr int   Bb   = 2;
constexpr int   Slen = 2048;
constexpr int   Hdim = 2048;
constexpr int   NHn  = 16;
constexpr int   HDd  = 128;
constexpr float QSCALE = 0.08838834764831845f; // 1/sqrt(128)

__device__ __forceinline__ bf16x8 ld8(const __bf16* p) { return *(const bf16x8*)p; }
__device__ __forceinline__ bf16x8 ld8(const float* p) {
    f32x4 a = *(const f32x4*)p, b = *(const f32x4*)(p + 4);
    bf16x8 r;
    r[0] = (__bf16)a[0]; r[1] = (__bf16)a[1]; r[2] = (__bf16)a[2]; r[3] = (__bf16)a[3];
    r[4] = (__bf16)b[0]; r[5] = (__bf16)b[1]; r[6] = (__bf16)b[2]; r[7] = (__bf16)b[3];
    return r;
}

// ---------------- convert+transpose: fp32 [R][C] -> bf16 [C][R] ----------------
__global__ __launch_bounds__(256) void transpose_cvt(const float* __restrict__ in,
                                                     __bf16* __restrict__ out,
                                                     int R, int C) {
    __shared__ float t[64][65];
    const int c0 = blockIdx.x * 64, r0 = blockIdx.y * 64;
    const int tx = threadIdx.x & 63, ty = threadIdx.x >> 6;
#pragma unroll
    for (int i = 0; i < 16; ++i) {
        int r = i * 4 + ty;
        t[r][tx] = in[(size_t)(r0 + r) * C + c0 + tx];
    }
    __syncthreads();
#pragma unroll
    for (int i = 0; i < 16; ++i) {
        int r = i * 4 + ty;
        out[(size_t)(c0 + r) * R + r0 + tx] = (__bf16)t[tx][r];
    }
}

// ---------------- GEMM (A row-major [M][K] (fp32 or bf16), Bt bf16 [N][K]) ----------------
// MODE 0: QKV projection epilogue -> scatter to Q (scaled), K, V (bf16 row-major)
// MODE 1: plain epilogue + fp32 bias -> fp32 Cout
template <int MODE, typename AT>
__global__ __launch_bounds__(256) void gemm_bt(
    const AT* __restrict__ A, const __bf16* __restrict__ Bt,
    const float* __restrict__ bias, int Kdim, int Ndim,
    float* __restrict__ Cout,
    __bf16* __restrict__ Qo, __bf16* __restrict__ Ko, __bf16* __restrict__ Vo) {
    __shared__ __bf16 As[128 * 32];
    __shared__ __bf16 Bs[128 * 32];
    const int tid = threadIdx.x;
    const int lane = tid & 63, wave = tid >> 6;
    const int quad = lane >> 4, l16 = lane & 15;
    const int wm = (wave >> 1) * 64, wn = (wave & 1) * 64;
    const int m0 = blockIdx.y * 128, n0 = blockIdx.x * 128;

    f32x4 acc[4][4] = {};

    for (int k0 = 0; k0 < Kdim; k0 += 32) {
        __syncthreads();
#pragma unroll
        for (int i = 0; i < 2; ++i) {
            int c = tid + i * 256;
            *(bf16x8*)(As + c * 8) = ld8(A  + (size_t)(m0 + (c >> 2)) * Kdim + k0 + (c & 3) * 8);
            *(bf16x8*)(Bs + c * 8) = ld8(Bt + (size_t)(n0 + (c >> 2)) * Kdim + k0 + (c & 3) * 8);
        }
        __syncthreads();
        bf16x8 af[4], bfr[4];
#pragma unroll
        for (int mi = 0; mi < 4; ++mi)
            af[mi] = *(const bf16x8*)(As + (wm + mi * 16 + l16) * 32 + quad * 8);
#pragma unroll
        for (int ni = 0; ni < 4; ++ni)
            bfr[ni] = *(const bf16x8*)(Bs + (wn + ni * 16 + l16) * 32 + quad * 8);
#pragma unroll
        for (int mi = 0; mi < 4; ++mi)
#pragma unroll
            for (int ni = 0; ni < 4; ++ni)
                acc[mi][ni] = __builtin_amdgcn_mfma_f32_16x16x32_bf16(
                    af[mi], bfr[ni], acc[mi][ni], 0, 0, 0);
    }

#pragma unroll
    for (int mi = 0; mi < 4; ++mi) {
#pragma unroll
        for (int r = 0; r < 4; ++r) {
            const int m = m0 + wm + mi * 16 + quad * 4 + r;
            const int b = m >> 11, s = m & 2047;
#pragma unroll
            for (int ni = 0; ni < 4; ++ni) {
                const int cc = n0 + wn + ni * 16 + l16;
                float val = acc[mi][ni][r] + bias[cc];
                if (MODE == 1) {
                    Cout[(size_t)m * Ndim + cc] = val;
                } else {
                    // column cc -> head h, within-head offset rr (3*HD = 384 per head)
                    const int h = cc / 384;
                    const int rr = cc - h * 384;
                    const size_t hb = ((size_t)(b * NHn + h) * Slen + s);
                    if (rr < 128)
                        Qo[hb * HDd + rr] = (__bf16)(val * QSCALE);
                    else if (rr < 256)
                        Ko[hb * HDd + (rr - 128)] = (__bf16)val;
                    else
                        Vo[hb * HDd + (rr - 256)] = (__bf16)val;
                }
            }
        }
    }
}

// ---------------- naive attention (correct-by-construction) ----------------
// grid (S/4, B*NH), block 256 = 4 waves; one wave per query row.
// Q pre-scaled. Q,K,V all [bh][S][HD] bf16 row-major. Causal via uniform loop bound.
__global__ __launch_bounds__(256) void attn_naive(const __bf16* __restrict__ Q,
                                                  const __bf16* __restrict__ K,
                                                  const __bf16* __restrict__ V,
                                                  __bf16* __restrict__ ctx) {
    const int lane = threadIdx.x & 63, wave = threadIdx.x >> 6;
    const int bh = blockIdx.y;
    const int b = bh >> 4, h = bh & 15;
    const int q = blockIdx.x * 4 + wave;
    const __bf16* Qr = Q + ((size_t)bh * Slen + q) * HDd;
    const __bf16* Kb = K + (size_t)bh * Slen * HDd;
    const __bf16* Vb = V + (size_t)bh * Slen * HDd;
    const int d0 = lane * 2;
    const float q0v = (float)Qr[d0], q1v = (float)Qr[d0 + 1];

    float m = -1e30f, l = 0.f, o0 = 0.f, o1 = 0.f;
    for (int k = 0; k <= q; ++k) {
        const __bf16* Kr = Kb + (size_t)k * HDd + d0;
        float part = q0v * (float)Kr[0] + q1v * (float)Kr[1];
        // full-wave butterfly: every lane ends with the complete 128-d dot
        part += __shfl_xor(part, 1);
        part += __shfl_xor(part, 2);
        part += __shfl_xor(part, 4);
        part += __shfl_xor(part, 8);
        part += __shfl_xor(part, 16);
        part += __shfl_xor(part, 32);
        const float mn    = fmaxf(m, part);
        const float alpha = __expf(m - mn);
        const float p     = __expf(part - mn);
        const __bf16* Vr = Vb + (size_t)k * HDd + d0;
        o0 = o0 * alpha + p * (float)Vr[0];
        o1 = o1 * alpha + p * (float)Vr[1];
        l  = l * alpha + p;
        m  = mn;
    }
    const size_t ob = ((size_t)b * Slen + q) * Hdim + h * HDd + d0;
    ctx[ob]     = (__bf16)(o0 / l);
    ctx[ob + 1] = (__bf16)(o1 / l);
}

extern "C" void kernel_launch(void* const* d_in, const int* in_sizes, int n_in,
                              void* d_out, int out_size, void* d_ws, size_t ws_size,
                              hipStream_t stream) {
    // Inputs are fp32 per the reference; output fp32.
    const float* hs   = (const float*)d_in[0];
    const float* wqkv = (const float*)d_in[1];
    const float* bqkv = (const float*)d_in[2];
    const float* wout = (const float*)d_in[3];
    const float* bout = (const float*)d_in[4];
    float* out = (float*)d_out;

    // workspace carve (bf16 elems): ~101 MB total
    __bf16* ws    = (__bf16*)d_ws;
    __bf16* wqkvT = ws;                          // [6144][2048] bf16
    __bf16* woutT = wqkvT + (size_t)6144 * 2048; // [2048][2048] bf16
    __bf16* Qs    = woutT + (size_t)2048 * 2048; // [B,NH,S,HD] (pre-scaled)
    __bf16* Kms   = Qs  + (size_t)Bb * NHn * Slen * HDd; // [B,NH,S,HD]
    __bf16* Vms   = Kms + (size_t)Bb * NHn * Slen * HDd; // [B,NH,S,HD]
    __bf16* ctx   = Vms + (size_t)Bb * NHn * Slen * HDd; // [B,S,H]

    transpose_cvt<<<dim3(6144 / 64, 2048 / 64), 256, 0, stream>>>(wqkv, wqkvT, 2048, 6144);
    transpose_cvt<<<dim3(2048 / 64, 2048 / 64), 256, 0, stream>>>(wout, woutT, 2048, 2048);
    gemm_bt<0, float><<<dim3(6144 / 128, 4096 / 128), 256, 0, stream>>>(
        hs, wqkvT, bqkv, Hdim, 3 * Hdim, nullptr, Qs, Kms, Vms);
    attn_naive<<<dim3(Slen / 4, Bb * NHn), 256, 0, stream>>>(Qs, Kms, Vms, ctx);
    gemm_bt<1, __bf16><<<dim3(2048 / 128, 4096 / 128), 256, 0, stream>>>(
        ctx, woutT, bout, Hdim, Hdim, out, nullptr, nullptr, nullptr);
}

// Round 6
// 694.618 us; speedup vs baseline: 7.3908x; 7.3908x over previous
//
#include <hip/hip_runtime.h>
#include <hip/hip_bf16.h>

typedef __bf16 bf16x8 __attribute__((ext_vector_type(8)));
typedef float  f32x4  __attribute__((ext_vector_type(4)));

constexpr int   Bb   = 2;
constexpr int   Slen = 2048;
constexpr int   Hdim = 2048;
constexpr int   NHn  = 16;
constexpr int   HDd  = 128;
constexpr float QSCALE = 0.08838834764831845f; // 1/sqrt(128)
constexpr float NEG    = -1e30f;

__device__ __forceinline__ bf16x8 ld8(const __bf16* p) { return *(const bf16x8*)p; }
__device__ __forceinline__ bf16x8 ld8(const float* p) {
    f32x4 a = *(const f32x4*)p, b = *(const f32x4*)(p + 4);
    bf16x8 r;
    r[0] = (__bf16)a[0]; r[1] = (__bf16)a[1]; r[2] = (__bf16)a[2]; r[3] = (__bf16)a[3];
    r[4] = (__bf16)b[0]; r[5] = (__bf16)b[1]; r[6] = (__bf16)b[2]; r[7] = (__bf16)b[3];
    return r;
}

// ---------------- convert+transpose: fp32 [R][C] -> bf16 [C][R] ----------------
__global__ __launch_bounds__(256) void transpose_cvt(const float* __restrict__ in,
                                                     __bf16* __restrict__ out,
                                                     int R, int C) {
    __shared__ float t[64][65];
    const int c0 = blockIdx.x * 64, r0 = blockIdx.y * 64;
    const int tx = threadIdx.x & 63, ty = threadIdx.x >> 6;
#pragma unroll
    for (int i = 0; i < 16; ++i) {
        int r = i * 4 + ty;
        t[r][tx] = in[(size_t)(r0 + r) * C + c0 + tx];
    }
    __syncthreads();
#pragma unroll
    for (int i = 0; i < 16; ++i) {
        int r = i * 4 + ty;
        out[(size_t)(c0 + r) * R + r0 + tx] = (__bf16)t[tx][r];
    }
}

// ---------------- GEMM (A row-major [M][K] (fp32 or bf16), Bt bf16 [N][K]) ----------------
// MODE 0: QKV projection epilogue -> scatter to Q (scaled), K row-major, V transposed
// MODE 1: plain epilogue + fp32 bias -> fp32 Cout
template <int MODE, typename AT>
__global__ __launch_bounds__(256) void gemm_bt(
    const AT* __restrict__ A, const __bf16* __restrict__ Bt,
    const float* __restrict__ bias, int Kdim, int Ndim,
    float* __restrict__ Cout,
    __bf16* __restrict__ Qo, __bf16* __restrict__ Ko, __bf16* __restrict__ Vto) {
    __shared__ __bf16 As[128 * 32];
    __shared__ __bf16 Bs[128 * 32];
    const int tid = threadIdx.x;
    const int lane = tid & 63, wave = tid >> 6;
    const int quad = lane >> 4, l16 = lane & 15;
    const int wm = (wave >> 1) * 64, wn = (wave & 1) * 64;
    const int m0 = blockIdx.y * 128, n0 = blockIdx.x * 128;

    f32x4 acc[4][4] = {};

    for (int k0 = 0; k0 < Kdim; k0 += 32) {
        __syncthreads();
#pragma unroll
        for (int i = 0; i < 2; ++i) {
            int c = tid + i * 256;
            *(bf16x8*)(As + c * 8) = ld8(A  + (size_t)(m0 + (c >> 2)) * Kdim + k0 + (c & 3) * 8);
            *(bf16x8*)(Bs + c * 8) = ld8(Bt + (size_t)(n0 + (c >> 2)) * Kdim + k0 + (c & 3) * 8);
        }
        __syncthreads();
        bf16x8 af[4], bfr[4];
#pragma unroll
        for (int mi = 0; mi < 4; ++mi)
            af[mi] = *(const bf16x8*)(As + (wm + mi * 16 + l16) * 32 + quad * 8);
#pragma unroll
        for (int ni = 0; ni < 4; ++ni)
            bfr[ni] = *(const bf16x8*)(Bs + (wn + ni * 16 + l16) * 32 + quad * 8);
#pragma unroll
        for (int mi = 0; mi < 4; ++mi)
#pragma unroll
            for (int ni = 0; ni < 4; ++ni)
                acc[mi][ni] = __builtin_amdgcn_mfma_f32_16x16x32_bf16(
                    af[mi], bfr[ni], acc[mi][ni], 0, 0, 0);
    }

#pragma unroll
    for (int mi = 0; mi < 4; ++mi) {
#pragma unroll
        for (int r = 0; r < 4; ++r) {
            const int m = m0 + wm + mi * 16 + quad * 4 + r;
            const int b = m >> 11, s = m & 2047;
#pragma unroll
            for (int ni = 0; ni < 4; ++ni) {
                const int cc = n0 + wn + ni * 16 + l16;
                float val = acc[mi][ni][r] + bias[cc];
                if (MODE == 1) {
                    Cout[(size_t)m * Ndim + cc] = val;
                } else {
                    // column cc -> head h, within-head offset rr (3*HD = 384 per head)
                    const int h = cc / 384;
                    const int rr = cc - h * 384;
                    const size_t hb = ((size_t)(b * NHn + h) * Slen + s);
                    if (rr < 128)
                        Qo[hb * HDd + rr] = (__bf16)(val * QSCALE);
                    else if (rr < 256)
                        Ko[hb * HDd + (rr - 128)] = (__bf16)val;
                    else
                        Vto[((size_t)(b * NHn + h) * HDd + (rr - 256)) * Slen + s] = (__bf16)val;
                }
            }
        }
    }
}

// ---------------- flash attention (causal, MFMA) ----------------
// grid: (S/64, B*NH). block 256 = 4 waves; wave handles 16 q-rows.
// Q pre-scaled. K [bh][S][HD], Vt [bh][HD][S], ctx bf16 [B][S][H].
__global__ __launch_bounds__(256) void attn_k(const __bf16* __restrict__ Q,
                                              const __bf16* __restrict__ Kmat,
                                              const __bf16* __restrict__ Vt,
                                              __bf16* __restrict__ ctx) {
    __shared__ __bf16 Ks[128 * 128];  // [key][d]  (reused for P: 4 x wave-private 16x128)
    __shared__ __bf16 Vs[128 * 128];  // [d][key]
    const int tid = threadIdx.x, lane = tid & 63, wave = tid >> 6;
    const int quad = lane >> 4, l16 = lane & 15;
    const int bh = blockIdx.y, qt = blockIdx.x;
    const int b = bh >> 4, h = bh & 15;
    const __bf16* Qb = Q    + (size_t)bh * Slen * HDd;
    const __bf16* Kb = Kmat + (size_t)bh * Slen * HDd;
    const __bf16* Vb = Vt   + (size_t)bh * HDd * Slen;
    const int q0 = qt * 64;
    const int qa = q0 + wave * 16 + l16;       // A-frag row (Q, P loads)
    const int qc = q0 + wave * 16 + quad * 4;  // C-layout base row

    bf16x8 qf[4];
#pragma unroll
    for (int kk = 0; kk < 4; ++kk)
        qf[kk] = *(const bf16x8*)(Qb + (size_t)qa * HDd + kk * 32 + quad * 8);

    f32x4 accO[8] = {};
    float m_i[4] = {NEG, NEG, NEG, NEG};
    float l_i[4] = {0.f, 0.f, 0.f, 0.f};

    const int ktiles = (q0 + 63) / 128 + 1;
    for (int kt = 0; kt < ktiles; ++kt) {
        const int kb0 = kt * 128;
        __syncthreads();  // previous iter's P/V reads done before restaging
        // stage K tile [128 keys][128 d] and V^T tile [128 d][128 keys]
        // 128 rows x 16 chunks of 8 elems; row = c>>4, chunk = c&15
#pragma unroll
        for (int i = 0; i < 8; ++i) {
            int c = tid + i * 256;
            *(bf16x8*)(Ks + c * 8) =
                *(const bf16x8*)(Kb + (size_t)(kb0 + (c >> 4)) * HDd + (c & 15) * 8);
            *(bf16x8*)(Vs + c * 8) =
                *(const bf16x8*)(Vb + (size_t)(c >> 4) * Slen + kb0 + (c & 15) * 8);
        }
        __syncthreads();

        // scores: wave's 16 q-rows x 128 keys
        f32x4 sc[8];
#pragma unroll
        for (int nk = 0; nk < 8; ++nk) {
            f32x4 z = {0.f, 0.f, 0.f, 0.f};
#pragma unroll
            for (int kk = 0; kk < 4; ++kk) {
                bf16x8 kf = *(const bf16x8*)(Ks + (nk * 16 + l16) * 128 + kk * 32 + quad * 8);
                z = __builtin_amdgcn_mfma_f32_16x16x32_bf16(qf[kk], kf, z, 0, 0, 0);
            }
            sc[nk] = z;
        }
        if (kt == ktiles - 1) {  // diagonal tile: causal mask
#pragma unroll
            for (int nk = 0; nk < 8; ++nk) {
                const int kg = kb0 + nk * 16 + l16;
#pragma unroll
                for (int r = 0; r < 4; ++r)
                    if (kg > qc + r) sc[nk][r] = NEG;
            }
        }
        // online softmax; row (quad*4+r) lives in the 16 lanes of this quad
#pragma unroll
        for (int r = 0; r < 4; ++r) {
            float mm = sc[0][r];
#pragma unroll
            for (int nk = 1; nk < 8; ++nk) mm = fmaxf(mm, sc[nk][r]);
            mm = fmaxf(mm, __shfl_xor(mm, 1));
            mm = fmaxf(mm, __shfl_xor(mm, 2));
            mm = fmaxf(mm, __shfl_xor(mm, 4));
            mm = fmaxf(mm, __shfl_xor(mm, 8));
            const float mnew = fmaxf(m_i[r], mm);
            const float alpha = __expf(m_i[r] - mnew);
            float ls = 0.f;
#pragma unroll
            for (int nk = 0; nk < 8; ++nk) {
                float p = __expf(sc[nk][r] - mnew);
                sc[nk][r] = p;
                ls += p;
            }
            ls += __shfl_xor(ls, 1);
            ls += __shfl_xor(ls, 2);
            ls += __shfl_xor(ls, 4);
            ls += __shfl_xor(ls, 8);
            l_i[r] = l_i[r] * alpha + ls;
            m_i[r] = mnew;
#pragma unroll
            for (int nd = 0; nd < 8; ++nd) accO[nd][r] *= alpha;
        }

        __syncthreads();  // all waves done reading Ks before P overwrites it
        __bf16* Ps = Ks + wave * 16 * 128;  // wave-private 16x128
#pragma unroll
        for (int nk = 0; nk < 8; ++nk)
#pragma unroll
            for (int r = 0; r < 4; ++r)
                Ps[(quad * 4 + r) * 128 + nk * 16 + l16] = (__bf16)sc[nk][r];
        __syncthreads();

        bf16x8 pf[4];
#pragma unroll
        for (int kk = 0; kk < 4; ++kk)
            pf[kk] = *(const bf16x8*)(Ps + l16 * 128 + kk * 32 + quad * 8);
#pragma unroll
        for (int nd = 0; nd < 8; ++nd)
#pragma unroll
            for (int kk = 0; kk < 4; ++kk) {
                bf16x8 vf = *(const bf16x8*)(Vs + (nd * 16 + l16) * 128 + kk * 32 + quad * 8);
                accO[nd] = __builtin_amdgcn_mfma_f32_16x16x32_bf16(pf[kk], vf, accO[nd], 0, 0, 0);
            }
    }

#pragma unroll
    for (int nd = 0; nd < 8; ++nd)
#pragma unroll
        for (int r = 0; r < 4; ++r) {
            const int s = q0 + wave * 16 + quad * 4 + r;
            const int d = nd * 16 + l16;
            const float o = accO[nd][r] / fmaxf(l_i[r], 1e-20f);
            ctx[((size_t)b * Slen + s) * Hdim + h * HDd + d] = (__bf16)o;
        }
}

extern "C" void kernel_launch(void* const* d_in, const int* in_sizes, int n_in,
                              void* d_out, int out_size, void* d_ws, size_t ws_size,
                              hipStream_t stream) {
    // Inputs are fp32 per the reference; output fp32.
    const float* hs   = (const float*)d_in[0];
    const float* wqkv = (const float*)d_in[1];
    const float* bqkv = (const float*)d_in[2];
    const float* wout = (const float*)d_in[3];
    const float* bout = (const float*)d_in[4];
    float* out = (float*)d_out;

    // workspace carve (bf16 elems): ~101 MB total
    __bf16* ws    = (__bf16*)d_ws;
    __bf16* wqkvT = ws;                          // [6144][2048] bf16
    __bf16* woutT = wqkvT + (size_t)6144 * 2048; // [2048][2048] bf16
    __bf16* Qs    = woutT + (size_t)2048 * 2048; // [B,NH,S,HD] (pre-scaled)
    __bf16* Kms   = Qs  + (size_t)Bb * NHn * Slen * HDd; // [B,NH,S,HD]
    __bf16* Vts   = Kms + (size_t)Bb * NHn * Slen * HDd; // [B,NH,HD,S]
    __bf16* ctx   = Vts + (size_t)Bb * NHn * Slen * HDd; // [B,S,H]

    transpose_cvt<<<dim3(6144 / 64, 2048 / 64), 256, 0, stream>>>(wqkv, wqkvT, 2048, 6144);
    transpose_cvt<<<dim3(2048 / 64, 2048 / 64), 256, 0, stream>>>(wout, woutT, 2048, 2048);
    gemm_bt<0, float><<<dim3(6144 / 128, 4096 / 128), 256, 0, stream>>>(
        hs, wqkvT, bqkv, Hdim, 3 * Hdim, nullptr, Qs, Kms, Vts);
    attn_k<<<dim3(Slen / 64, Bb * NHn), 256, 0, stream>>>(Qs, Kms, Vts, ctx);
    gemm_bt<1, __bf16><<<dim3(2048 / 128, 4096 / 128), 256, 0, stream>>>(
        ctx, woutT, bout, Hdim, Hdim, out, nullptr, nullptr, nullptr);
}

// Round 7
// 498.246 us; speedup vs baseline: 10.3037x; 1.3941x over previous
//
#include <hip/hip_runtime.h>
#include <hip/hip_bf16.h>

typedef __bf16 bf16x8 __attribute__((ext_vector_type(8)));
typedef float  f32x4  __attribute__((ext_vector_type(4)));

constexpr int   Bb   = 2;
constexpr int   Slen = 2048;
constexpr int   Hdim = 2048;
constexpr int   NHn  = 16;
constexpr int   HDd  = 128;
constexpr int   LDP  = 136;   // padded LDS row stride (128+8): bank-conflict-free (2-way)
constexpr float QSCALE = 0.08838834764831845f; // 1/sqrt(128)
constexpr float NEG    = -1e30f;

// async global->LDS, 16B per lane; LDS dest = wave-uniform base + lane*16 (m97 pattern)
__device__ __forceinline__ void gld16(const __bf16* g, __bf16* l) {
    __builtin_amdgcn_global_load_lds(
        (__attribute__((address_space(1))) void*)(uintptr_t)(const void*)g,
        (__attribute__((address_space(3))) void*)l, 16, 0, 0);
}

// ---------------- fp32 -> bf16 bulk convert (vectorized) ----------------
__global__ __launch_bounds__(256) void cvt_bf16(const float* __restrict__ in,
                                                __bf16* __restrict__ out) {
    const size_t i = (size_t)(blockIdx.x * 256 + threadIdx.x) * 8;
    f32x4 a = *(const f32x4*)(in + i), b = *(const f32x4*)(in + i + 4);
    bf16x8 r;
    r[0] = (__bf16)a[0]; r[1] = (__bf16)a[1]; r[2] = (__bf16)a[2]; r[3] = (__bf16)a[3];
    r[4] = (__bf16)b[0]; r[5] = (__bf16)b[1]; r[6] = (__bf16)b[2]; r[7] = (__bf16)b[3];
    *(bf16x8*)(out + i) = r;
}

// ---------------- convert+transpose: fp32 [R][C] -> bf16 [C][R] ----------------
__global__ __launch_bounds__(256) void transpose_cvt(const float* __restrict__ in,
                                                     __bf16* __restrict__ out,
                                                     int R, int C) {
    __shared__ float t[64][65];
    const int c0 = blockIdx.x * 64, r0 = blockIdx.y * 64;
    const int tx = threadIdx.x & 63, ty = threadIdx.x >> 6;
#pragma unroll
    for (int i = 0; i < 16; ++i) {
        int r = i * 4 + ty;
        t[r][tx] = in[(size_t)(r0 + r) * C + c0 + tx];
    }
    __syncthreads();
#pragma unroll
    for (int i = 0; i < 16; ++i) {
        int r = i * 4 + ty;
        out[(size_t)(c0 + r) * R + r0 + tx] = (__bf16)t[tx][r];
    }
}

// ---------------- GEMM (A bf16 row-major [M][K], Bt bf16 [N][K]) ----------------
// m97-style: global_load_lds width-16 staging, 128x128x32 tile, 4 waves x 4x4 MFMA
// MODE 0: QKV epilogue -> scatter Q (scaled), K row-major, V transposed
// MODE 1: plain epilogue + fp32 bias -> fp32 Cout
template <int MODE>
__global__ __launch_bounds__(256) void gemm_bt(
    const __bf16* __restrict__ A, const __bf16* __restrict__ Bt,
    const float* __restrict__ bias, int Kdim, int Ndim,
    float* __restrict__ Cout,
    __bf16* __restrict__ Qo, __bf16* __restrict__ Ko, __bf16* __restrict__ Vto) {
    __shared__ __bf16 As[128 * 32];
    __shared__ __bf16 Bs[128 * 32];
    const int tid = threadIdx.x;
    const int lane = tid & 63, wave = tid >> 6;
    const int quad = lane >> 4, l16 = lane & 15;
    const int wm = (wave >> 1) * 64, wn = (wave & 1) * 64;
    const int m0 = blockIdx.y * 128, n0 = blockIdx.x * 128;

    f32x4 acc[4][4] = {};

    for (int k0 = 0; k0 < Kdim; k0 += 32) {
        __syncthreads();
#pragma unroll
        for (int i = 0; i < 2; ++i) {
            int c = tid + i * 256;
            gld16(A  + (size_t)(m0 + (c >> 2)) * Kdim + k0 + (c & 3) * 8, As + c * 8);
            gld16(Bt + (size_t)(n0 + (c >> 2)) * Kdim + k0 + (c & 3) * 8, Bs + c * 8);
        }
        __syncthreads();
        bf16x8 af[4], bfr[4];
#pragma unroll
        for (int mi = 0; mi < 4; ++mi)
            af[mi] = *(const bf16x8*)(As + (wm + mi * 16 + l16) * 32 + quad * 8);
#pragma unroll
        for (int ni = 0; ni < 4; ++ni)
            bfr[ni] = *(const bf16x8*)(Bs + (wn + ni * 16 + l16) * 32 + quad * 8);
#pragma unroll
        for (int mi = 0; mi < 4; ++mi)
#pragma unroll
            for (int ni = 0; ni < 4; ++ni)
                acc[mi][ni] = __builtin_amdgcn_mfma_f32_16x16x32_bf16(
                    af[mi], bfr[ni], acc[mi][ni], 0, 0, 0);
    }

#pragma unroll
    for (int mi = 0; mi < 4; ++mi) {
#pragma unroll
        for (int r = 0; r < 4; ++r) {
            const int m = m0 + wm + mi * 16 + quad * 4 + r;
            const int b = m >> 11, s = m & 2047;
#pragma unroll
            for (int ni = 0; ni < 4; ++ni) {
                const int cc = n0 + wn + ni * 16 + l16;
                float val = acc[mi][ni][r] + bias[cc];
                if (MODE == 1) {
                    Cout[(size_t)m * Ndim + cc] = val;
                } else {
                    const int h = cc / 384;       // 3*HD = 384 per head
                    const int rr = cc - h * 384;
                    const size_t hb = ((size_t)(b * NHn + h) * Slen + s);
                    if (rr < 128)
                        Qo[hb * HDd + rr] = (__bf16)(val * QSCALE);
                    else if (rr < 256)
                        Ko[hb * HDd + (rr - 128)] = (__bf16)val;
                    else
                        Vto[((size_t)(b * NHn + h) * HDd + (rr - 256)) * Slen + s] = (__bf16)val;
                }
            }
        }
    }
}

// ---------------- flash attention (causal, MFMA, padded LDS) ----------------
// grid: (S/64, B*NH), block 256 = 4 waves; wave handles 16 q-rows.
// qt reversed so heaviest (most k-tiles) blocks dispatch first.
__global__ __launch_bounds__(256) void attn_k(const __bf16* __restrict__ Q,
                                              const __bf16* __restrict__ Kmat,
                                              const __bf16* __restrict__ Vt,
                                              __bf16* __restrict__ ctx) {
    __shared__ __bf16 Ks[128 * LDP];  // [key][d]  (reused for P: wave-private 16xLDP)
    __shared__ __bf16 Vs[128 * LDP];  // [d][key]
    const int tid = threadIdx.x, lane = tid & 63, wave = tid >> 6;
    const int quad = lane >> 4, l16 = lane & 15;
    const int bh = blockIdx.y;
    const int qt = gridDim.x - 1 - blockIdx.x;  // heavy blocks first
    const int b = bh >> 4, h = bh & 15;
    const __bf16* Qb = Q    + (size_t)bh * Slen * HDd;
    const __bf16* Kb = Kmat + (size_t)bh * Slen * HDd;
    const __bf16* Vb = Vt   + (size_t)bh * HDd * Slen;
    const int q0 = qt * 64;
    const int qa = q0 + wave * 16 + l16;       // A-frag row
    const int qc = q0 + wave * 16 + quad * 4;  // C-layout base row

    bf16x8 qf[4];
#pragma unroll
    for (int kk = 0; kk < 4; ++kk)
        qf[kk] = *(const bf16x8*)(Qb + (size_t)qa * HDd + kk * 32 + quad * 8);

    f32x4 accO[8] = {};
    float m_i[4] = {NEG, NEG, NEG, NEG};
    float l_i[4] = {0.f, 0.f, 0.f, 0.f};

    const int ktiles = (q0 + 63) / 128 + 1;
    for (int kt = 0; kt < ktiles; ++kt) {
        const int kb0 = kt * 128;
        __syncthreads();
        // stage K [128 key][128 d] and V^T [128 d][128 key]; row = c>>4, chunk = c&15
#pragma unroll
        for (int i = 0; i < 8; ++i) {
            int c = tid + i * 256;
            *(bf16x8*)(Ks + (c >> 4) * LDP + (c & 15) * 8) =
                *(const bf16x8*)(Kb + (size_t)(kb0 + (c >> 4)) * HDd + (c & 15) * 8);
            *(bf16x8*)(Vs + (c >> 4) * LDP + (c & 15) * 8) =
                *(const bf16x8*)(Vb + (size_t)(c >> 4) * Slen + kb0 + (c & 15) * 8);
        }
        __syncthreads();

        f32x4 sc[8];
#pragma unroll
        for (int nk = 0; nk < 8; ++nk) {
            f32x4 z = {0.f, 0.f, 0.f, 0.f};
#pragma unroll
            for (int kk = 0; kk < 4; ++kk) {
                bf16x8 kf = *(const bf16x8*)(Ks + (nk * 16 + l16) * LDP + kk * 32 + quad * 8);
                z = __builtin_amdgcn_mfma_f32_16x16x32_bf16(qf[kk], kf, z, 0, 0, 0);
            }
            sc[nk] = z;
        }
        if (kt == ktiles - 1) {  // diagonal tile: causal mask
#pragma unroll
            for (int nk = 0; nk < 8; ++nk) {
                const int kg = kb0 + nk * 16 + l16;
#pragma unroll
                for (int r = 0; r < 4; ++r)
                    if (kg > qc + r) sc[nk][r] = NEG;
            }
        }
        // online softmax across the quad's 16 lanes
#pragma unroll
        for (int r = 0; r < 4; ++r) {
            float mm = sc[0][r];
#pragma unroll
            for (int nk = 1; nk < 8; ++nk) mm = fmaxf(mm, sc[nk][r]);
            mm = fmaxf(mm, __shfl_xor(mm, 1));
            mm = fmaxf(mm, __shfl_xor(mm, 2));
            mm = fmaxf(mm, __shfl_xor(mm, 4));
            mm = fmaxf(mm, __shfl_xor(mm, 8));
            const float mnew = fmaxf(m_i[r], mm);
            const float alpha = __expf(m_i[r] - mnew);
            float ls = 0.f;
#pragma unroll
            for (int nk = 0; nk < 8; ++nk) {
                float p = __expf(sc[nk][r] - mnew);
                sc[nk][r] = p;
                ls += p;
            }
            ls += __shfl_xor(ls, 1);
            ls += __shfl_xor(ls, 2);
            ls += __shfl_xor(ls, 4);
            ls += __shfl_xor(ls, 8);
            l_i[r] = l_i[r] * alpha + ls;
            m_i[r] = mnew;
#pragma unroll
            for (int nd = 0; nd < 8; ++nd) accO[nd][r] *= alpha;
        }

        __syncthreads();  // all waves done reading Ks before P overwrites it
        __bf16* Ps = Ks + wave * 16 * LDP;  // wave-private 16 rows
#pragma unroll
        for (int nk = 0; nk < 8; ++nk)
#pragma unroll
            for (int r = 0; r < 4; ++r)
                Ps[(quad * 4 + r) * LDP + nk * 16 + l16] = (__bf16)sc[nk][r];
        __syncthreads();

        bf16x8 pf[4];
#pragma unroll
        for (int kk = 0; kk < 4; ++kk)
            pf[kk] = *(const bf16x8*)(Ps + l16 * LDP + kk * 32 + quad * 8);
#pragma unroll
        for (int nd = 0; nd < 8; ++nd)
#pragma unroll
            for (int kk = 0; kk < 4; ++kk) {
                bf16x8 vf = *(const bf16x8*)(Vs + (nd * 16 + l16) * LDP + kk * 32 + quad * 8);
                accO[nd] = __builtin_amdgcn_mfma_f32_16x16x32_bf16(pf[kk], vf, accO[nd], 0, 0, 0);
            }
    }

#pragma unroll
    for (int nd = 0; nd < 8; ++nd)
#pragma unroll
        for (int r = 0; r < 4; ++r) {
            const int s = q0 + wave * 16 + quad * 4 + r;
            const int d = nd * 16 + l16;
            const float o = accO[nd][r] / fmaxf(l_i[r], 1e-20f);
            ctx[((size_t)b * Slen + s) * Hdim + h * HDd + d] = (__bf16)o;
        }
}

extern "C" void kernel_launch(void* const* d_in, const int* in_sizes, int n_in,
                              void* d_out, int out_size, void* d_ws, size_t ws_size,
                              hipStream_t stream) {
    const float* hs   = (const float*)d_in[0];
    const float* wqkv = (const float*)d_in[1];
    const float* bqkv = (const float*)d_in[2];
    const float* wout = (const float*)d_in[3];
    const float* bout = (const float*)d_in[4];
    float* out = (float*)d_out;

    // workspace carve (bf16 elems): ~101 MB. hsb aliases ctx (hsb consumed by
    // QKV GEMM before attn_k overwrites the region with ctx).
    __bf16* ws    = (__bf16*)d_ws;
    __bf16* wqkvT = ws;                          // [6144][2048]
    __bf16* woutT = wqkvT + (size_t)6144 * 2048; // [2048][2048]
    __bf16* Qs    = woutT + (size_t)2048 * 2048; // [B,NH,S,HD] pre-scaled
    __bf16* Kms   = Qs  + (size_t)Bb * NHn * Slen * HDd; // [B,NH,S,HD]
    __bf16* Vts   = Kms + (size_t)Bb * NHn * Slen * HDd; // [B,NH,HD,S]
    __bf16* ctx   = Vts + (size_t)Bb * NHn * Slen * HDd; // [B,S,H] (= hsb)
    __bf16* hsb   = ctx;

    cvt_bf16<<<(Bb * Slen * Hdim) / (256 * 8), 256, 0, stream>>>(hs, hsb);
    transpose_cvt<<<dim3(6144 / 64, 2048 / 64), 256, 0, stream>>>(wqkv, wqkvT, 2048, 6144);
    transpose_cvt<<<dim3(2048 / 64, 2048 / 64), 256, 0, stream>>>(wout, woutT, 2048, 2048);
    gemm_bt<0><<<dim3(6144 / 128, 4096 / 128), 256, 0, stream>>>(
        hsb, wqkvT, bqkv, Hdim, 3 * Hdim, nullptr, Qs, Kms, Vts);
    attn_k<<<dim3(Slen / 64, Bb * NHn), 256, 0, stream>>>(Qs, Kms, Vts, ctx);
    gemm_bt<1><<<dim3(2048 / 128, 4096 / 128), 256, 0, stream>>>(
        ctx, woutT, bout, Hdim, Hdim, out, nullptr, nullptr, nullptr);
}